// Round 5
// baseline (1203.203 us; speedup 1.0000x reference)
//
#include <hip/hip_runtime.h>
#include <math.h>

#define BB 8
#define CC 64
#define NCAP 16
#define HH 96
#define WW 96
#define PP (HH*WW)      // 9216
#define BNN (BB*NCAP)   // 128
#define EPSN 1e-5f

typedef short short8 __attribute__((ext_vector_type(8)));
typedef unsigned short u16x8 __attribute__((ext_vector_type(8)));
typedef unsigned short u16x4 __attribute__((ext_vector_type(4)));
typedef float float4v __attribute__((ext_vector_type(4)));

__device__ __forceinline__ float bf2f(unsigned short u){
  union{unsigned int i; float f;} x; x.i = ((unsigned int)u)<<16; return x.f;
}
__device__ __forceinline__ unsigned short f2bf(float f){
  union{float f; unsigned int i;} x; x.f=f;
  unsigned int r = x.i + 0x7fffu + ((x.i>>16)&1u);
  return (unsigned short)(r>>16);
}
__device__ __forceinline__ float4v mfma16(short8 a, short8 b, float4v c){
  return __builtin_amdgcn_mfma_f32_16x16x32_bf16(a, b, c, 0, 0, 0);
}

// ---------------- block reduction helpers (256-thread blocks) ----------------
__device__ __forceinline__ float blkred_sum(float v, float* red4){
  int tid = threadIdx.x; int lane = tid & 63, wv = tid >> 6;
  #pragma unroll
  for (int off=32; off>0; off>>=1) v += __shfl_down(v, off, 64);
  __syncthreads();
  if (lane == 0) red4[wv] = v;
  __syncthreads();
  return red4[0] + red4[1] + red4[2] + red4[3];
}
__device__ __forceinline__ float blkred_max(float v, float* red4){
  int tid = threadIdx.x; int lane = tid & 63, wv = tid >> 6;
  #pragma unroll
  for (int off=32; off>0; off>>=1) v = fmaxf(v, __shfl_down(v, off, 64));
  __syncthreads();
  if (lane == 0) red4[wv] = v;
  __syncthreads();
  return fmaxf(fmaxf(red4[0], red4[1]), fmaxf(red4[2], red4[3]));
}

// ---------------- KPRE: transpose tg[b][c][p] fp32 -> tgt[b][p][c] bf16 ----------------
__global__ void kpre_tgt(const float* __restrict__ tg, unsigned short* __restrict__ tgt){
  int b = blockIdx.x/36, pc = blockIdx.x - (blockIdx.x/36)*36;
  int p = pc*256 + threadIdx.x;
  unsigned short vals[CC];
  #pragma unroll 8
  for (int c=0;c<CC;c++) vals[c] = f2bf(tg[((size_t)b*CC + c)*PP + p]);
  u16x8* dst = (u16x8*)&tgt[((size_t)b*PP + p)*CC];
  #pragma unroll
  for (int j=0;j<8;j++){
    u16x8 v;
    #pragma unroll
    for (int e=0;e<8;e++) v[e] = vals[j*8+e];
    dst[j] = v;
  }
}

// ---------------- KW: conv1 weights [o][c][k9] fp32 -> Wt[k9][o][c] bf16 ----------------
__global__ void kw_bf16(const float* __restrict__ w1, unsigned short* __restrict__ Wt){
  int i = blockIdx.x*256 + threadIdx.x;   // 36864 exactly
  int o = i/576; int rem = i - o*576; int c = rem/9; int tap = rem - c*9;
  Wt[(tap*CC + o)*CC + c] = f2bf(w1[i]);
}

// ---------------- K0: per-(b,c) sums of sr (t) and tg (S1,S2) ----------------
__global__ void k0_colstats(const float* __restrict__ sr, const float* __restrict__ tg,
                            float* __restrict__ t, float* __restrict__ S1, float* __restrict__ S2){
  int row = blockIdx.x;                 // b*CC + c, 512 rows
  const float* srp = sr + (size_t)row * PP;
  const float* tgp = tg + (size_t)row * PP;
  float s0=0.f, a1=0.f, a2=0.f;
  for (int p = threadIdx.x; p < PP; p += 256){
    s0 += srp[p];
    float v = tgp[p];
    a1 += v; a2 += v*v;
  }
  __shared__ float red4[4];
  s0 = blkred_sum(s0, red4);
  a1 = blkred_sum(a1, red4);
  a2 = blkred_sum(a2, red4);
  if (threadIdx.x == 0){ t[row]=s0; S1[row]=a1; S2[row]=a2; }
}

// ------- K1: op = W_n.vec + biasmul*w_b ; opn ; u = W_n^T.opn ; bu --------
__global__ void k_update(const float* __restrict__ Wm, const float* __restrict__ wb,
                         const float* __restrict__ vec, float biasmul, int perB,
                         float* __restrict__ opv, float* __restrict__ uv, float* __restrict__ bu){
  int bn = blockIdx.x; int n = bn & (NCAP-1); int b = bn >> 4;
  int c = threadIdx.x;                  // 64 threads
  __shared__ float Wsh[CC*65];
  __shared__ float vsh[CC];
  __shared__ float opsh[CC];
  vsh[c] = perB ? vec[b*CC + c] : vec[bn*CC + c];
  const float* Wn = Wm + (size_t)n*CC*CC;
  for (int i=c;i<CC*CC;i+=64){ int r=i>>6, k=i&63; Wsh[r*65+k]=Wn[i]; }
  __syncthreads();
  float acc = biasmul * wb[n*CC + c];
  #pragma unroll 8
  for (int k=0;k<CC;k++) acc += Wsh[c*65+k]*vsh[k];
  opv[bn*CC+c] = acc;
  float ss = acc*acc;
  #pragma unroll
  for (int off=32;off>0;off>>=1) ss += __shfl_down(ss, off, 64);
  ss = __shfl(ss, 0, 64);
  float inv = 1.0f / fmaxf(sqrtf(ss), 1e-12f);
  opsh[c] = acc * inv;
  __syncthreads();
  float uacc = 0.f;
  #pragma unroll 8
  for (int k=0;k<CC;k++) uacc += opsh[k] * Wsh[k*65+c];
  uv[bn*CC+c] = uacc;
  float bb = opsh[c]*wb[n*CC+c];
  #pragma unroll
  for (int off=32;off>0;off>>=1) bb += __shfl_down(bb, off, 64);
  if (c==0) bu[bn] = bb;
}

// ------- K2F: fused d-pass + softmax partials + weighted partial sums -------
__global__ __launch_bounds__(128) void k2f_dpass(
    const float* __restrict__ sr, const float* __restrict__ uv,
    const float* __restrict__ bu, float* __restrict__ dbuf,
    float* __restrict__ partm, float* __restrict__ partz,
    float* __restrict__ prt, int writed){
  int b = blockIdx.x / 72; int pc = blockIdx.x - b*72;
  int tid = threadIdx.x;
  int p = pc*128 + tid;
  __shared__ float ush[NCAP][CC];
  __shared__ float bush[NCAP];
  __shared__ float msh[NCAP];
  __shared__ float wsh[NCAP*132];   // d then exp-weights, stride 132 (16B-aligned)
  __shared__ float srsh[CC*132];    // sr tile [c][p], stride 132
  for (int i=tid;i<NCAP*CC;i+=128) ush[i>>6][i&63] = uv[b*NCAP*CC + i];
  if (tid < NCAP) bush[tid] = bu[b*NCAP+tid];
  __syncthreads();
  float acc[NCAP];
  #pragma unroll
  for (int n=0;n<NCAP;n++) acc[n]=bush[n];
  #pragma unroll 4
  for (int c=0;c<CC;c++){
    float v = sr[((size_t)b*CC + c)*PP + p];
    srsh[c*132+tid] = v;
    #pragma unroll
    for (int n=0;n<NCAP;n++) acc[n] += ush[n][c]*v;
  }
  #pragma unroll
  for (int n=0;n<NCAP;n++){
    wsh[n*132+tid] = acc[n];
    if (writed) dbuf[((size_t)(b*NCAP+n))*PP + p] = acc[n];
  }
  __syncthreads();
  // softmax partials: 16 teams of 8 lanes; team n reduces its 128 d-values
  {
    int n = tid >> 3, seg = tid & 7;
    float m = -1e30f;
    #pragma unroll
    for (int i=0;i<16;i++) m = fmaxf(m, wsh[n*132+seg*16+i]);
    #pragma unroll
    for (int off=1; off<8; off<<=1) m = fmaxf(m, __shfl_xor(m, off, 64));
    float z = 0.f;
    #pragma unroll
    for (int i=0;i<16;i++) z += __expf(wsh[n*132+seg*16+i] - m);
    #pragma unroll
    for (int off=1; off<8; off<<=1) z += __shfl_xor(z, off, 64);
    if (seg == 0){
      partm[(b*NCAP + n)*72 + pc] = m;
      partz[(b*NCAP + n)*72 + pc] = z;
      msh[n] = m;
    }
  }
  __syncthreads();
  #pragma unroll
  for (int n=0;n<NCAP;n++) wsh[n*132+tid] = __expf(wsh[n*132+tid]-msh[n]);
  __syncthreads();
  // weighted partial sums: wave-half handles 8 capsules, lane = channel
  {
    int c = tid & 63, half = tid >> 6;
    float acc8[8];
    #pragma unroll
    for (int i=0;i<8;i++) acc8[i]=0.f;
    const float4* sp = (const float4*)&srsh[c*132];
    #pragma unroll 4
    for (int k=0;k<32;k++){
      float4 sv = sp[k];
      #pragma unroll
      for (int i=0;i<8;i++){
        float4 wv = *(const float4*)&wsh[(half*8+i)*132+4*k];
        acc8[i] += wv.x*sv.x + wv.y*sv.y + wv.z*sv.z + wv.w*sv.w;
      }
    }
    float* pb = prt + (((size_t)b*72+pc)*NCAP + half*8)*CC + c;
    #pragma unroll
    for (int i=0;i<8;i++) pb[(size_t)i*CC] = acc8[i];
  }
}

// ------- K_ITER: fused softmax-combine + rv fold + capsule update (per bn) -------
__global__ void k_iter(const float* __restrict__ prt, const float* __restrict__ partm,
                       const float* __restrict__ partz, const float* __restrict__ Wm,
                       const float* __restrict__ wb, float* __restrict__ mrow,
                       float* __restrict__ zrow, float* __restrict__ opv,
                       float* __restrict__ uv, float* __restrict__ bu){
  int bn = blockIdx.x; int n = bn & (NCAP-1); int b = bn >> 4;
  int c = threadIdx.x;                  // 64 threads
  // phase 1: combine per-chunk softmax partials (72 chunks)
  float m1 = partm[bn*72 + c];
  float m2 = (c < 8) ? partm[bn*72 + 64 + c] : -1e30f;
  float mm = fmaxf(m1, m2);
  #pragma unroll
  for (int off=32;off>0;off>>=1) mm = fmaxf(mm, __shfl_xor(mm, off, 64));
  float z = partz[bn*72 + c]*__expf(m1 - mm);
  if (c < 8) z += partz[bn*72 + 64 + c]*__expf(m2 - mm);
  #pragma unroll
  for (int off=32;off>0;off>>=1) z += __shfl_xor(z, off, 64);
  if (c==0){ mrow[bn]=mm; zrow[bn]=z; }
  float invZ = 1.0f/z;
  // phase 2: fold weighted partials -> rv (kept in registers)
  float s = 0.f;
  #pragma unroll 8
  for (int pc=0;pc<72;pc++){
    float w = __expf(partm[bn*72+pc] - mm);
    s += prt[(((size_t)b*72+pc)*NCAP + n)*CC + c] * w;
  }
  float rvc = s*invZ;
  // phase 3: capsule update (k_update body, biasmul=1)
  __shared__ float Wsh[CC*65];
  __shared__ float vsh[CC];
  __shared__ float opsh[CC];
  vsh[c] = rvc;
  const float* Wn = Wm + (size_t)n*CC*CC;
  for (int i=c;i<CC*CC;i+=64){ int r=i>>6, k=i&63; Wsh[r*65+k]=Wn[i]; }
  __syncthreads();
  float acc = wb[n*CC + c];
  #pragma unroll 8
  for (int k=0;k<CC;k++) acc += Wsh[c*65+k]*vsh[k];
  opv[bn*CC+c] = acc;
  float ss = acc*acc;
  #pragma unroll
  for (int off=32;off>0;off>>=1) ss += __shfl_down(ss, off, 64);
  ss = __shfl(ss, 0, 64);
  float inv = 1.0f / fmaxf(sqrtf(ss), 1e-12f);
  opsh[c] = acc * inv;
  __syncthreads();
  float uacc = 0.f;
  #pragma unroll 8
  for (int k=0;k<CC;k++) uacc += opsh[k] * Wsh[k*65+c];
  uv[bn*CC+c] = uacc;
  float bb = opsh[c]*wb[n*CC+c];
  #pragma unroll
  for (int off=32;off>0;off>>=1) bb += __shfl_down(bb, off, 64);
  if (c==0) bu[bn] = bb;
}

// ---------------- K6: write final cof output ----------------
__global__ void k6_cofout(const float* __restrict__ dbuf, const float* __restrict__ mrow,
                          const float* __restrict__ zrow, float* __restrict__ cof){
  int bn = blockIdx.y;
  int p = blockIdx.x*256 + threadIdx.x;
  float m=mrow[bn], invz=1.0f/zrow[bn];
  cof[(size_t)bn*PP+p] = __expf(dbuf[(size_t)bn*PP+p]-m)*invz;
}

// ---------------- K7: GN1 closed-form affine (A,D per b,n,c) + zero partials ----------------
__global__ void k7_gn1(const float* __restrict__ S1, const float* __restrict__ S2,
                       const float* __restrict__ opv, const float* __restrict__ g1,
                       const float* __restrict__ b1, float* __restrict__ Aaff,
                       float* __restrict__ Daff, float* __restrict__ gn2s,
                       float* __restrict__ gn2q, float* __restrict__ in2s,
                       float* __restrict__ in2q, float* __restrict__ lossout){
  int bn = blockIdx.x; int b = bn >> 4;
  int c = threadIdx.x;                  // 64 threads
  __shared__ float e1[CC], e2[CC], mu[16], ri[16];
  float op = opv[bn*CC+c];
  float s1 = S1[b*CC+c], s2 = S2[b*CC+c];
  e1[c] = s1 + (float)PP*op;
  e2[c] = s2 + 2.0f*op*s1 + (float)PP*op*op;
  __syncthreads();
  if (c < 16){
    float m  = (e1[4*c]+e1[4*c+1]+e1[4*c+2]+e1[4*c+3])*(1.0f/(4.0f*PP));
    float qq = (e2[4*c]+e2[4*c+1]+e2[4*c+2]+e2[4*c+3])*(1.0f/(4.0f*PP));
    mu[c]=m; ri[c]=rsqrtf(qq-m*m+EPSN);
    gn2s[bn*16+c]=0.f; gn2q[bn*16+c]=0.f;
  }
  if (bn==0){
    in2s[c]=0.f; in2s[CC+c]=0.f; in2q[c]=0.f; in2q[CC+c]=0.f;
    if (c==0) lossout[0]=0.f;
  }
  __syncthreads();
  int g = c>>2;
  float A = ri[g]*g1[c];
  Aaff[bn*CC+c]=A;
  Daff[bn*CC+c]=(op-mu[g])*A + b1[c];
}

// ---------------- K8: conv1 via bf16 MFMA implicit GEMM ----------------
// tile 8x16 per block (6 blocks/CU), y1 PIXEL-MAJOR [bn][p][o] bf16.
// Epilogue bounces acc through LDS so global stores fully cover 128-B lines.
__global__ __launch_bounds__(256, 6) void k8_conv1_mfma(
    const unsigned short* __restrict__ tgt, const unsigned short* __restrict__ Wt,
    const float* __restrict__ c1b, const float* __restrict__ Aaff,
    const float* __restrict__ Daff, unsigned short* __restrict__ y1b,
    float* __restrict__ gn2s, float* __restrict__ gn2q){
  int blk = blockIdx.x;
  int bn = blk/72, tt = blk - bn*72;     // 12 row-tiles x 6 col-tiles
  int ty = tt/6, tx = tt - ty*6;
  int y0 = ty*8, x0 = tx*16;
  int b = bn >> 4;
  int tid = threadIdx.x, w = tid>>6, lane = tid&63, quad = lane>>4, col16 = lane&15;

  __shared__ unsigned short xh[10*18*72];   // staging halo [row][col][ch(72)] ; reused as ybuf
  __shared__ float Ash[CC], Dsh[CC];
  if (tid < CC){ Ash[tid]=Aaff[bn*CC+tid]; Dsh[tid]=Daff[bn*CC+tid]; }
  __syncthreads();

  const unsigned short* tgb = tgt + (size_t)b*PP*CC;
  for (int task = tid; task < 1440; task += 256){   // 180 px x 8 ch-octets
    int j = task & 7, pi = task >> 3;
    int row = pi/18, col = pi - row*18;
    int gy = y0 + row - 1, gx = x0 + col - 1;
    u16x8 ov;
    if ((unsigned)gy < (unsigned)HH && (unsigned)gx < (unsigned)WW){
      u16x8 iv = *(const u16x8*)(tgb + ((size_t)(gy*WW+gx))*CC + j*8);
      #pragma unroll
      for (int e=0;e<8;e++){
        float f = bf2f(iv[e]);
        f = fmaxf(Ash[j*8+e]*f + Dsh[j*8+e], 0.f);
        ov[e] = f2bf(f);
      }
    } else {
      #pragma unroll
      for (int e=0;e<8;e++) ov[e]=0;
    }
    *(u16x8*)&xh[(row*18+col)*72 + j*8] = ov;
  }
  __syncthreads();

  float4v acc[4][2];
  #pragma unroll
  for (int mt=0;mt<4;mt++)
    #pragma unroll
    for (int ri=0;ri<2;ri++)
      #pragma unroll
      for (int e=0;e<4;e++) acc[mt][ri][e]=0.f;

  const unsigned short* xb0 = &xh[((2*w)*18 + col16)*72 + quad*8];
  const unsigned short* wbase = Wt + (size_t)(col16*CC + quad*8);
  #pragma unroll
  for (int tap=0; tap<9; ++tap){
    const int dy = tap/3, dx = tap - (tap/3)*3;
    const int toff = (dy*18 + dx)*72;
    #pragma unroll
    for (int chunk=0; chunk<2; ++chunk){
      short8 a[4];
      #pragma unroll
      for (int mt=0;mt<4;mt++)
        a[mt] = *(const short8*)(wbase + tap*4096 + mt*1024 + chunk*32);
      short8 bf[2];
      #pragma unroll
      for (int ri=0;ri<2;ri++)
        bf[ri] = *(const short8*)(xb0 + toff + ri*(18*72) + chunk*32);
      #pragma unroll
      for (int mt=0;mt<4;mt++)
        #pragma unroll
        for (int ri=0;ri<2;ri++)
          acc[mt][ri] = mfma16(a[mt], bf[ri], acc[mt][ri]);
    }
  }

  // epilogue: +bias -> LDS ybuf [128px][72ch], GN2 partials, then coalesced store
  __syncthreads();                       // all LDS reads done; xh reusable
  unsigned short* ybuf = xh;             // [pix=row*16+col][72] u16
  #pragma unroll
  for (int mt=0;mt<4;mt++){
    float gs=0.f, gq=0.f;
    #pragma unroll
    for (int ri=0;ri<2;ri++){
      u16x4 pv;
      #pragma unroll
      for (int e=0;e<4;e++){
        int o = mt*16 + quad*4 + e;
        float v = acc[mt][ri][e] + c1b[o];
        pv[e] = f2bf(v);
        gs += v; gq += v*v;
      }
      *(u16x4*)&ybuf[((2*w+ri)*16 + col16)*72 + mt*16 + quad*4] = pv;
    }
    #pragma unroll
    for (int off=1; off<16; off<<=1){
      gs += __shfl_xor(gs, off, 64);
      gq += __shfl_xor(gq, off, 64);
    }
    if (col16==0){
      atomicAdd(&gn2s[bn*16 + mt*4 + quad], gs);
      atomicAdd(&gn2q[bn*16 + mt*4 + quad], gq);
    }
  }
  __syncthreads();
  unsigned short* ybn = y1b + (size_t)bn*PP*CC;
  #pragma unroll
  for (int pass=0; pass<4; ++pass){
    int row = pass*2 + (tid>>7);
    int chunk = tid & 127;               // 128 x 16B chunks per row (16 px x 128 B)
    int pix = row*16 + (chunk>>3), c8 = chunk&7;
    u16x8 v = *(const u16x8*)&ybuf[pix*72 + c8*8];
    *(u16x8*)&ybn[(size_t)((y0+row)*WW + x0)*CC + chunk*8] = v;
  }
}

// ---------------- K10: conv2 64->1 3x3 from pixel-major bf16 y1 (GN2 finalize fused) ----------------
__global__ __launch_bounds__(256) void k10_conv2(
    const unsigned short* __restrict__ y1b, const float* __restrict__ w2,
    const float* __restrict__ b2, const float* __restrict__ gn2s,
    const float* __restrict__ gn2q, const float* __restrict__ g2c,
    const float* __restrict__ b2c, float* __restrict__ mskout){
  int blk=blockIdx.x; int bn=blk/36; int tt=blk-bn*36;
  int y0=(tt/3)*8, x0=(tt%3)*32;
  int tid=threadIdx.x;
  __shared__ unsigned short xh2[10*34*72];   // [row][col][ch(72 pad)] raw bf16 y1
  __shared__ float wsh2[CC*9];
  __shared__ float Ash[CC], Dsh[CC];
  __shared__ float mg[16], rg[16];
  for (int i=tid;i<CC*9;i+=256) wsh2[i]=w2[i];
  if (tid<16){
    float m = gn2s[bn*16+tid]*(1.0f/(4.0f*PP));
    float q = gn2q[bn*16+tid]*(1.0f/(4.0f*PP));
    mg[tid]=m; rg[tid]=rsqrtf(q-m*m+EPSN);
  }
  __syncthreads();
  if (tid<CC){
    float A = rg[tid>>2]*g2c[tid];
    Ash[tid]=A; Dsh[tid]=b2c[tid]-mg[tid>>2]*A;
  }

  const unsigned short* yb = y1b + (size_t)bn*PP*CC;
  for (int task=tid; task<2720; task+=256){   // 340 pixels x 8 ch-octets
    int j = task & 7, pi = task >> 3;
    int row = pi/34, col = pi - row*34;
    int gy = y0 + row - 1, gx = x0 + col - 1;
    u16x8 iv;
    if ((unsigned)gy < (unsigned)HH && (unsigned)gx < (unsigned)WW){
      iv = *(const u16x8*)(yb + ((size_t)(gy*WW+gx))*CC + j*8);
    } else {
      #pragma unroll
      for (int e=0;e<8;e++) iv[e]=0;
    }
    *(u16x8*)&xh2[(row*34+col)*72 + j*8] = iv;
  }
  __syncthreads();

  int xi = tid&31, yi = tid>>5;
  float acc = 0.f;
  for (int t=0; t<9; ++t){
    int kh = t/3, kw = t - kh*3;
    int gy2 = y0 + yi + kh - 1, gx2 = x0 + xi + kw - 1;
    if ((unsigned)gy2 < (unsigned)HH && (unsigned)gx2 < (unsigned)WW){
      const unsigned short* px = &xh2[((yi+kh)*34 + xi+kw)*72];
      #pragma unroll
      for (int oct=0; oct<8; ++oct){
        u16x8 v = *(const u16x8*)(px + oct*8);
        #pragma unroll
        for (int e=0;e<8;e++){
          int c = oct*8 + e;
          float xv = fmaxf(Ash[c]*bf2f(v[e]) + Dsh[c], 0.f);
          acc += wsh2[c*9 + t] * xv;
        }
      }
    }
  }
  acc += b2[0];
  mskout[(size_t)bn*PP + (size_t)(y0+yi)*WW + (x0+xi)] = acc;
}

// ---------------- K11: per-(b,n) msk stats + IN1 affine + loss (atomic mean) ----------------
__global__ void k11_mskstats(const float* __restrict__ msk, const float* __restrict__ in1g,
                             const float* __restrict__ in1b, float* __restrict__ in1A,
                             float* __restrict__ in1D, float* __restrict__ lossout){
  int bn = blockIdx.x; int n = bn & (NCAP-1);
  const float* mp = msk + (size_t)bn*PP;
  __shared__ float red4[4];
  float mx=-1e30f, s=0.f, q=0.f;
  for (int p=threadIdx.x;p<PP;p+=256){ float v=mp[p]; mx=fmaxf(mx,v); s+=v; q+=v*v; }
  mx = blkred_max(mx, red4);
  s  = blkred_sum(s, red4);
  q  = blkred_sum(q, red4);
  float z=0.f, sy=0.f, sx=0.f, syy=0.f, sxx=0.f;
  for (int p=threadIdx.x;p<PP;p+=256){
    float e = __expf(mp[p]-mx);
    int py = p/WW, px = p - py*WW;
    float iy = -1.0f + py*(2.0f/95.0f);
    float ix = -1.0f + px*(2.0f/95.0f);
    z+=e; sy+=e*iy; sx+=e*ix; syy+=e*iy*iy; sxx+=e*ix*ix;
  }
  z=blkred_sum(z,red4); sy=blkred_sum(sy,red4); sx=blkred_sum(sx,red4);
  syy=blkred_sum(syy,red4); sxx=blkred_sum(sxx,red4);
  if (threadIdx.x==0){
    float invz=1.0f/z;
    float ey=sy*invz, ex=sx*invz;
    float lv=(syy*invz-ey*ey)+(sxx*invz-ex*ex);
    atomicAdd(lossout, lv*(1.0f/128.0f));
    float mu=s*(1.0f/PP), var=q*(1.0f/PP)-mu*mu;
    float A=rsqrtf(var+EPSN)*in1g[n];
    in1A[bn]=A; in1D[bn]=in1b[n]-mu*A;
  }
}

// ---------------- K13: gen-block stage 1: g2 = c3.relu(IN1(msk)) + IN2 partials ----------------
__global__ void k13_gen1(const float* __restrict__ msk, const float* __restrict__ in1A,
                         const float* __restrict__ in1D, const float* __restrict__ c3w,
                         const float* __restrict__ c3b, float* __restrict__ g2,
                         float* __restrict__ in2s, float* __restrict__ in2q){
  int b = blockIdx.x/36; int pc = blockIdx.x - b*36;
  int p = pc*256+threadIdx.x;
  __shared__ float wsh[NCAP*NCAP];
  __shared__ float Ash[NCAP], Dsh[NCAP], bsh[NCAP];
  if (threadIdx.x < NCAP*NCAP) wsh[threadIdx.x] = c3w[threadIdx.x];
  if (threadIdx.x < NCAP){
    Ash[threadIdx.x]=in1A[b*NCAP+threadIdx.x];
    Dsh[threadIdx.x]=in1D[b*NCAP+threadIdx.x];
    bsh[threadIdx.x]=c3b[threadIdx.x];
  }
  __syncthreads();
  float h[NCAP];
  #pragma unroll
  for (int n=0;n<NCAP;n++)
    h[n] = fmaxf(0.f, Ash[n]*msk[(size_t)(b*NCAP+n)*PP+p] + Dsh[n]);
  float g[NCAP];
  #pragma unroll
  for (int o=0;o<NCAP;o++){
    float a = bsh[o];
    #pragma unroll
    for (int n=0;n<NCAP;n++) a += wsh[o*NCAP+n]*h[n];
    g[o]=a;
    g2[(size_t)(b*NCAP+o)*PP+p]=a;
  }
  int lane = threadIdx.x & 63;
  #pragma unroll
  for (int o=0;o<NCAP;o++){
    float a=g[o], q=g[o]*g[o];
    #pragma unroll
    for (int off=32;off>0;off>>=1){ a+=__shfl_down(a,off,64); q+=__shfl_down(q,off,64); }
    if (lane==0){ atomicAdd(&in2s[b*NCAP+o],a); atomicAdd(&in2q[b*NCAP+o],q); }
  }
}

// ---------------- K15: rec = sigmoid(c4.relu(IN2(g2))) (IN2 finalize fused) ----------------
__global__ void k15_rec(const float* __restrict__ g2, const float* __restrict__ in2s,
                        const float* __restrict__ in2q, const float* __restrict__ in2g,
                        const float* __restrict__ in2b, const float* __restrict__ c4w,
                        const float* __restrict__ c4b, float* __restrict__ rec){
  int b = blockIdx.x/36; int pc = blockIdx.x - b*36;
  int p = pc*256+threadIdx.x;
  __shared__ float wsh[3*NCAP], Ash[NCAP], Dsh[NCAP], bsh[3];
  if (threadIdx.x<3*NCAP) wsh[threadIdx.x]=c4w[threadIdx.x];
  if (threadIdx.x<NCAP){
    float m=in2s[b*NCAP+threadIdx.x]*(1.0f/PP);
    float q=in2q[b*NCAP+threadIdx.x]*(1.0f/PP);
    float A=rsqrtf(q-m*m+EPSN)*in2g[threadIdx.x];
    Ash[threadIdx.x]=A; Dsh[threadIdx.x]=in2b[threadIdx.x]-m*A;
  }
  if (threadIdx.x<3) bsh[threadIdx.x]=c4b[threadIdx.x];
  __syncthreads();
  float h[NCAP];
  #pragma unroll
  for (int o=0;o<NCAP;o++)
    h[o]=fmaxf(0.f, Ash[o]*g2[(size_t)(b*NCAP+o)*PP+p]+Dsh[o]);
  #pragma unroll
  for (int j=0;j<3;j++){
    float z=bsh[j];
    #pragma unroll
    for (int o=0;o<NCAP;o++) z += wsh[j*NCAP+o]*h[o];
    rec[(size_t)(b*3+j)*PP+p] = 1.0f/(1.0f+__expf(-z));
  }
}

// ---------------- K16: op_out[b,n,c,p] = op[b,n,c]*msk[b,n,p] ----------------
__global__ void k16_opout(const float* __restrict__ opv, const float* __restrict__ msk,
                          float* __restrict__ out){
  int bn = blockIdx.x / 9; int pt = blockIdx.x - bn*9;
  int base = pt*1024;
  __shared__ float ms[1024];
  __shared__ float opl[CC];
  for (int i=threadIdx.x;i<1024;i+=256) ms[i]=msk[(size_t)bn*PP+base+i];
  if (threadIdx.x<CC) opl[threadIdx.x]=opv[bn*CC+threadIdx.x];
  __syncthreads();
  float4 mv = ((const float4*)ms)[threadIdx.x];
  float* obase = out + (size_t)bn*CC*PP + base;
  #pragma unroll 4
  for (int c=0;c<CC;c++){
    float ov = opl[c];
    ((float4*)(obase + (size_t)c*PP))[threadIdx.x] = make_float4(ov*mv.x,ov*mv.y,ov*mv.z,ov*mv.w);
  }
}

// =======================================================================
extern "C" void kernel_launch(void* const* d_in, const int* in_sizes, int n_in,
                              void* d_out, int out_size, void* d_ws, size_t ws_size,
                              hipStream_t stream){
  const float* sr   = (const float*)d_in[0];
  const float* tg   = (const float*)d_in[1];
  const float* w_w  = (const float*)d_in[2];
  const float* w_b  = (const float*)d_in[3];
  const float* gn1g = (const float*)d_in[4];
  const float* gn1b = (const float*)d_in[5];
  const float* c1w  = (const float*)d_in[6];
  const float* c1b  = (const float*)d_in[7];
  const float* gn2g = (const float*)d_in[8];
  const float* gn2b = (const float*)d_in[9];
  const float* c2w  = (const float*)d_in[10];
  const float* c2b  = (const float*)d_in[11];
  const float* in1g = (const float*)d_in[12];
  const float* in1b = (const float*)d_in[13];
  const float* c3w  = (const float*)d_in[14];
  const float* c3b  = (const float*)d_in[15];
  const float* in2g = (const float*)d_in[16];
  const float* in2b = (const float*)d_in[17];
  const float* c4w  = (const float*)d_in[18];
  const float* c4b  = (const float*)d_in[19];
  float* out = (float*)d_out;
  float* ws  = (float*)d_ws;

  // workspace layout (floats) — byte-identical footprint to the proven layout
  float* t_   = ws + 0;
  float* S1   = ws + 512;
  float* S2   = ws + 1024;
  float* opv  = ws + 1536;
  float* uv   = ws + 9728;
  float* bu   = ws + 17920;
  float* mrow = ws + 18048;
  float* zrow = ws + 18176;
  float* Aaff = ws + 26496;
  float* Daff = ws + 34688;
  float* gn2s = ws + 42880;
  float* gn2q = ws + 44928;
  float* in1A = ws + 63360;
  float* in1D = ws + 63488;
  float* in2s = ws + 63744;
  float* in2q = ws + 63872;
  float* dbuf = ws + 65536;              // 1,179,648 floats
  float* g2   = ws + 65536 + 1179648;    // 1,179,648 floats

  // d_out region reuse (everything here is overwritten by k16/mask/rec/etc later):
  unsigned short* y1b = (unsigned short*)d_out;                                  // 150,994,944 B
  unsigned short* tgt = (unsigned short*)((char*)d_out + 150994944);             // 9,437,184 B
  unsigned short* Wt  = (unsigned short*)((char*)d_out + 160432128);             // 73,728 B
  float* prt   = (float*)((char*)d_out + 160505856);                             // 2,359,296 B
  float* partm = (float*)((char*)d_out + 162865152);                             // 36,864 B
  float* partz = (float*)((char*)d_out + 162902016);                             // 36,864 B
  float* mskout  = out + 75497472;
  float* recout  = out + 76677120;
  float* lossout = out + 76898304;
  float* cofout  = out + 76898305;

  kpre_tgt<<<BB*36, 256, 0, stream>>>(tg, tgt);
  kw_bf16<<<144, 256, 0, stream>>>(c1w, Wt);
  k0_colstats<<<BB*CC, 256, 0, stream>>>(sr, tg, t_, S1, S2);
  k_update<<<BNN, 64, 0, stream>>>(w_w, w_b, t_, (float)PP, 1, opv, uv, bu);
  for (int it=0; it<3; ++it){
    k2f_dpass<<<BB*72, 128, 0, stream>>>(sr, uv, bu, dbuf, partm, partz, prt, it==2 ? 1 : 0);
    k_iter<<<BNN, 64, 0, stream>>>(prt, partm, partz, w_w, w_b, mrow, zrow, opv, uv, bu);
  }
  k6_cofout<<<dim3(36, BNN), 256, 0, stream>>>(dbuf, mrow, zrow, cofout);
  k7_gn1<<<BNN, 64, 0, stream>>>(S1, S2, opv, gn1g, gn1b, Aaff, Daff, gn2s, gn2q, in2s, in2q, lossout);
  k8_conv1_mfma<<<BNN*72, 256, 0, stream>>>(tgt, Wt, c1b, Aaff, Daff, y1b, gn2s, gn2q);
  k10_conv2<<<BNN*36, 256, 0, stream>>>(y1b, c2w, c2b, gn2s, gn2q, gn2g, gn2b, mskout);
  k11_mskstats<<<BNN, 256, 0, stream>>>(mskout, in1g, in1b, in1A, in1D, lossout);
  k13_gen1<<<BB*36, 256, 0, stream>>>(mskout, in1A, in1D, c3w, c3b, g2, in2s, in2q);
  k15_rec<<<BB*36, 256, 0, stream>>>(g2, in2s, in2q, in2g, in2b, c4w, c4b, recout);
  k16_opout<<<BNN*9, 256, 0, stream>>>(opv, mskout, out);
}